// Round 1
// baseline (782.043 us; speedup 1.0000x reference)
//
#include <hip/hip_runtime.h>
#include <hip/hip_bf16.h>

#define B_ 8
#define S_ 2048
#define H_ 512
#define P_ 16
#define K_ 256
#define M_TOT (B_*S_)      // 16384
#define TILE_M 128

typedef short bf8v __attribute__((ext_vector_type(8)));   // 8 x bf16 (MFMA operand)
typedef float f4v  __attribute__((ext_vector_type(4)));   // MFMA accumulator

// ---- device-global scratch (recomputed from inputs on every call) ----
__device__ unsigned short g_hidden[M_TOT*H_];   // bf16 hidden, [token][h]
__device__ unsigned short g_w1t[P_*K_*H_];      // bf16 w1 transposed: [p][k_out][h]
__device__ unsigned short g_w2t[P_*H_*K_];      // bf16 w2 transposed: [p][h][k_in]
__device__ float g_bias1[P_*K_];                // embed@w1 + b1
__device__ float g_pooled[B_*H_];
__device__ float g_probs[B_*P_];
__device__ float g_bias2w[B_*H_];               // sum_p probs*b2
__device__ float g_partial[M_TOT*H_];           // expert-group-1 partial output

__device__ __forceinline__ unsigned short f2bf(float x){
  unsigned int u = __builtin_bit_cast(unsigned int, x);
  u += 0x7fffu + ((u >> 16) & 1u);              // round-to-nearest-even
  return (unsigned short)(u >> 16);
}

// exact GELU: 0.5*x*(1+erf(x/sqrt(2))), erf via A&S 7.1.26 (|err|<1.5e-7)
__device__ __forceinline__ float gelu_exact(float x){
  float z  = x * 0.70710678f;
  float az = fabsf(z);
  float t  = 1.0f / (1.0f + 0.3275911f * az);
  float poly = t*(0.254829592f + t*(-0.284496736f + t*(1.421413741f +
               t*(-1.453152027f + t*1.061405429f))));
  float e = __expf(-az*az);
  float erfv = 1.0f - poly*e;
  erfv = (z < 0.0f) ? -erfv : erfv;
  return 0.5f * x * (1.0f + erfv);
}

// ---------- pre-pass: pooled mean over S ----------
__global__ void pool_kernel(const float* __restrict__ hs){
  int b  = blockIdx.x >> 5;          // 8 batches
  int hg = blockIdx.x & 31;          // 32 h-groups of 16
  int hh = threadIdx.x & 15;
  int ss = threadIdx.x >> 4;         // 16 s-lanes
  int h  = hg*16 + hh;
  const float* p = hs + ((size_t)b*S_ + ss)*H_ + h;
  float acc = 0.0f;
  for (int s = ss; s < S_; s += 16) { acc += *p; p += 16*H_; }
  __shared__ float red[16][17];
  red[ss][hh] = acc;
  __syncthreads();
  if (ss == 0){
    float t = 0.0f;
    #pragma unroll
    for (int i=0;i<16;++i) t += red[i][hh];
    g_pooled[b*H_ + h] = t * (1.0f/S_);
  }
}

// ---------- pre-pass: logits, softmax, bias2w ----------
__global__ void routing_kernel(const float* __restrict__ head_w,
                               const float* __restrict__ head_b,
                               const float* __restrict__ b2){
  __shared__ float logits[B_][P_];
  __shared__ float sprob[B_][P_];
  int w = threadIdx.x >> 6, lane = threadIdx.x & 63;
  for (int i = 0; i < 16; ++i){                   // 128 (b,p) pairs / 8 waves
    int pair = w*16 + i; int b = pair >> 4; int p = pair & 15;
    float acc = 0.0f;
    for (int h = lane; h < H_; h += 64) acc += g_pooled[b*H_+h]*head_w[p*H_+h];
    for (int off=32; off; off>>=1) acc += __shfl_down(acc, off);
    if (lane==0) logits[b][p] = acc + head_b[p];
  }
  __syncthreads();
  if (threadIdx.x < B_){
    int b = threadIdx.x;
    float mx = -1e30f;
    #pragma unroll
    for (int p=0;p<P_;++p) mx = fmaxf(mx, logits[b][p]);
    float e[P_]; float s = 0.0f;
    #pragma unroll
    for (int p=0;p<P_;++p){ e[p] = __expf(logits[b][p]-mx); s += e[p]; }
    float inv = 1.0f/s;
    #pragma unroll
    for (int p=0;p<P_;++p){ float pr = e[p]*inv; g_probs[b*P_+p] = pr; sprob[b][p] = pr; }
  }
  __syncthreads();
  for (int idx = threadIdx.x; idx < B_*H_; idx += blockDim.x){
    int b = idx >> 9, h = idx & (H_-1);
    float a = 0.0f;
    #pragma unroll
    for (int p=0;p<P_;++p) a += sprob[b][p]*b2[p*H_+h];
    g_bias2w[idx] = a;
  }
}

// ---------- pre-pass: hidden fp32 -> bf16 ----------
__global__ void cvt_hidden(const float* __restrict__ x){
  size_t i = (size_t)blockIdx.x*blockDim.x + threadIdx.x;   // over M*H/4
  float4 a = ((const float4*)x)[i];
  ushort4 o; o.x=f2bf(a.x); o.y=f2bf(a.y); o.z=f2bf(a.z); o.w=f2bf(a.w);
  ((ushort4*)g_hidden)[i] = o;
}

// ---------- pre-pass: transpose+convert weights: in[p][R][C] f32 -> out[p][C][R] bf16 ----------
__global__ void transpose_cvt(const float* __restrict__ in, int R, int C, int which){
  unsigned short* out = which ? g_w2t : g_w1t;
  int nrt = R >> 5, nct = C >> 5;
  int p   = blockIdx.x / (nrt*nct);
  int rem = blockIdx.x % (nrt*nct);
  int rt = rem / nct, ct = rem % nct;
  int tx = threadIdx.x & 31, ty = threadIdx.x >> 5;    // 32 x 8
  __shared__ float t[32][33];
  const float* ip = in + (size_t)p*R*C + (size_t)(rt*32 + ty)*C + ct*32 + tx;
  #pragma unroll
  for (int k=0;k<4;++k) t[ty + 8*k][tx] = ip[(size_t)8*k*C];
  __syncthreads();
  unsigned short* op = out + (size_t)p*R*C + (size_t)(ct*32 + ty)*R + rt*32 + tx;
  #pragma unroll
  for (int k=0;k<4;++k) op[(size_t)8*k*R] = f2bf(t[tx][ty + 8*k]);
}

// ---------- pre-pass: bias1[p][k] = embed[p]@w1[p][:,k] + b1[p][k] ----------
__global__ void bias1_kernel(const float* __restrict__ embeds,
                             const float* __restrict__ w1,
                             const float* __restrict__ b1){
  int p = blockIdx.x >> 3, kg = blockIdx.x & 7;
  int ks = threadIdx.x & 31, hs = threadIdx.x >> 5;   // 32 k x 8 h-lanes
  int kk = kg*32 + ks;
  float acc = 0.0f;
  for (int h = hs; h < H_; h += 8)
    acc += embeds[p*H_ + h] * w1[((size_t)p*H_ + h)*K_ + kk];
  __shared__ float red[8][33];
  red[hs][ks] = acc; __syncthreads();
  if (hs==0){
    float t = 0.0f;
    #pragma unroll
    for (int i=0;i<8;++i) t += red[i][ks];
    g_bias1[p*K_ + kk] = t + b1[p*K_+kk];
  }
}

// ---------- main fused expert-MLP kernel ----------
// grid = 256 blocks: (tile = bid>>1) x (expert-group = bid&1); 512 thr = 8 waves (2M x 2N)
__global__ __launch_bounds__(512, 2) void main_kernel(float* __restrict__ out){
  __shared__ unsigned short mid[TILE_M * K_];   // 64 KiB, XOR-swizzled
  const int tile = blockIdx.x >> 1;
  const int grp  = blockIdx.x & 1;
  const int tid  = threadIdx.x;
  const int w    = tid >> 6;
  const int lane = tid & 63;
  const int wm = w >> 1, wn = w & 1;
  const int l15 = lane & 15, lhi = lane >> 4;
  const int b = tile >> 4;                       // 16 tiles per batch
  const int row0 = tile*TILE_M + wm*32;

  const unsigned short* Abase = g_hidden + (size_t)(row0 + l15)*H_ + lhi*8;

  f4v oacc[2][16];
  #pragma unroll
  for (int i=0;i<2;++i)
    #pragma unroll
    for (int j=0;j<16;++j) oacc[i][j] = {0.f,0.f,0.f,0.f};

  for (int pi = 0; pi < 8; ++pi){
    const int p = grp*8 + pi;
    const float prob = g_probs[b*P_ + p];
    const unsigned short* w1p = g_w1t + (size_t)p*K_*H_;
    const unsigned short* w2p = g_w2t + (size_t)p*H_*K_;

    // ----- layer 1: mid = prob * gelu(hidden @ w1 + bias1); wave cols = wn*128 .. +128
    #pragma unroll
    for (int half = 0; half < 2; ++half){
      const int ncol0 = wn*128 + half*64;
      f4v acc[2][4];
      #pragma unroll
      for (int i=0;i<2;++i)
        #pragma unroll
        for (int j=0;j<4;++j) acc[i][j] = {0.f,0.f,0.f,0.f};
      const unsigned short* Bp = w1p + (size_t)(ncol0 + l15)*H_ + lhi*8;
      #pragma unroll 2
      for (int ks = 0; ks < 16; ++ks){
        bf8v a0 = *(const bf8v*)(Abase + ks*32);
        bf8v a1 = *(const bf8v*)(Abase + 16*H_ + ks*32);
        #pragma unroll
        for (int nt = 0; nt < 4; ++nt){
          bf8v bv = *(const bf8v*)(Bp + (size_t)nt*16*H_ + ks*32);
          acc[0][nt] = __builtin_amdgcn_mfma_f32_16x16x32_bf16(a0, bv, acc[0][nt], 0,0,0);
          acc[1][nt] = __builtin_amdgcn_mfma_f32_16x16x32_bf16(a1, bv, acc[1][nt], 0,0,0);
        }
      }
      #pragma unroll
      for (int nt=0; nt<4; ++nt){
        const int col  = ncol0 + nt*16 + l15;
        const float bias = g_bias1[p*K_ + col];
        #pragma unroll
        for (int mt=0; mt<2; ++mt){
          #pragma unroll
          for (int j=0;j<4;++j){
            const int r = wm*32 + mt*16 + lhi*4 + j;
            float v = acc[mt][nt][j] + bias;
            v = gelu_exact(v) * prob;
            mid[(r*K_ + col) ^ ((r&7)<<3)] = f2bf(v);
          }
        }
      }
    }
    __syncthreads();

    // ----- layer 2: oacc += mid @ w2; wave cols = wn*256 .. +256
    #pragma unroll
    for (int half=0; half<2; ++half){
      const unsigned short* Bp2 = w2p + (size_t)(wn*256 + half*128 + l15)*K_ + lhi*8;
      #pragma unroll 2
      for (int ks=0; ks<8; ++ks){
        const int r0 = wm*32 + l15;
        const int r1 = r0 + 16;
        bf8v a0 = *(const bf8v*)&mid[(r0*K_ + ks*32 + lhi*8) ^ ((r0&7)<<3)];
        bf8v a1 = *(const bf8v*)&mid[(r1*K_ + ks*32 + lhi*8) ^ ((r1&7)<<3)];
        #pragma unroll
        for (int nt=0; nt<8; ++nt){
          bf8v bv = *(const bf8v*)(Bp2 + (size_t)nt*16*K_ + ks*32);
          oacc[0][half*8+nt] = __builtin_amdgcn_mfma_f32_16x16x32_bf16(a0, bv, oacc[0][half*8+nt], 0,0,0);
          oacc[1][half*8+nt] = __builtin_amdgcn_mfma_f32_16x16x32_bf16(a1, bv, oacc[1][half*8+nt], 0,0,0);
        }
      }
    }
    __syncthreads();
  }

  float* outp = grp ? g_partial : out;
  #pragma unroll
  for (int ntt=0; ntt<16; ++ntt){
    const int col = wn*256 + ntt*16 + l15;
    const float extra = grp ? 0.0f : g_bias2w[b*H_ + col];
    #pragma unroll
    for (int mt=0; mt<2; ++mt){
      #pragma unroll
      for (int j=0;j<4;++j){
        const int r = row0 + mt*16 + lhi*4 + j;
        outp[(size_t)r*H_ + col] = oacc[mt][ntt][j] + extra;
      }
    }
  }
}

// ---------- final: out += partial ----------
__global__ void sum_kernel(float* __restrict__ out){
  size_t i = (size_t)blockIdx.x*blockDim.x + threadIdx.x;   // over M*H/4
  float4 a = ((const float4*)out)[i];
  const float4 c = ((const float4*)g_partial)[i];
  a.x += c.x; a.y += c.y; a.z += c.z; a.w += c.w;
  ((float4*)out)[i] = a;
}

extern "C" void kernel_launch(void* const* d_in, const int* in_sizes, int n_in,
                              void* d_out, int out_size, void* d_ws, size_t ws_size,
                              hipStream_t stream){
  const float* hidden = (const float*)d_in[0];
  const float* head_w = (const float*)d_in[1];
  const float* head_b = (const float*)d_in[2];
  const float* embeds = (const float*)d_in[3];
  const float* w1     = (const float*)d_in[4];
  const float* b1     = (const float*)d_in[5];
  const float* w2     = (const float*)d_in[6];
  const float* b2     = (const float*)d_in[7];
  float* out = (float*)d_out;
  (void)in_sizes; (void)n_in; (void)out_size; (void)d_ws; (void)ws_size;

  pool_kernel   <<<B_*32, 256, 0, stream>>>(hidden);
  routing_kernel<<<1, 512, 0, stream>>>(head_w, head_b, b2);
  cvt_hidden    <<<(M_TOT*H_/4)/256, 256, 0, stream>>>(hidden);
  transpose_cvt <<<P_*(H_/32)*(K_/32), 256, 0, stream>>>(w1, H_, K_, 0);
  transpose_cvt <<<P_*(K_/32)*(H_/32), 256, 0, stream>>>(w2, K_, H_, 1);
  bias1_kernel  <<<P_*8, 256, 0, stream>>>(embeds, w1, b1);
  main_kernel   <<<2*(M_TOT/TILE_M), 512, 0, stream>>>(out);
  sum_kernel    <<<(M_TOT*H_/4)/256, 256, 0, stream>>>(out);
}